// Round 2
// baseline (458.684 us; speedup 1.0000x reference)
//
#include <hip/hip_runtime.h>

// Problem constants (B,S,H fixed by the reference)
#define Bn 4
#define Sn 256
#define Hn 768
#define Pn 32896        // Sn*(Sn+1)/2
#define Mn 1024         // Bn*Sn

typedef float v4f __attribute__((ext_vector_type(4)));  // native vec for nontemporal

// ---------------- GEMM: g/v = X @ W^T (both halves), bias folded into g ----
// g[m,o] = sum_h X[m,h] * W[o*1536 + h]        + bias[o]
// v[m,o] = sum_h X[m,h] * W[o*1536 + 768 + h]
#define BM 64
#define BN 64
#define BK 32
#define LDP 4   // LDS pad (keeps rows 16B-aligned, breaks pow2 stride)

__global__ __launch_bounds__(256) void gemm_gv_kernel(
    const float* __restrict__ X,     // (1024, 768)
    const float* __restrict__ W,     // (768, 1536)
    const float* __restrict__ bias,  // (768)
    float* __restrict__ g,           // (1024, 768)
    float* __restrict__ v)           // (1024, 768)
{
    __shared__ float Xt[BK][BM + LDP];    // [k][m]
    __shared__ float Wgt[BK][BN + LDP];   // [k][o]
    __shared__ float Wvt[BK][BN + LDP];   // [k][o]

    const int tid = threadIdx.x;
    const int m0 = blockIdx.x * BM;
    const int n0 = blockIdx.y * BN;
    const int tx = tid & 15;        // 0..15  (cols / o)
    const int ty = tid >> 4;        // 0..15  (rows / m)
    const int lr = tid >> 3;        // 0..31  load row
    const int lk = (tid & 7) << 2;  // 0..28  load k offset (float4)

    float accg[4][4] = {};
    float accv[4][4] = {};

    for (int k0 = 0; k0 < Hn; k0 += BK) {
#pragma unroll
        for (int half = 0; half < 2; ++half) {
            const int r = lr + half * 32;
            const float4 xq = *(const float4*)(X + (size_t)(m0 + r) * Hn + k0 + lk);
            Xt[lk + 0][r] = xq.x; Xt[lk + 1][r] = xq.y;
            Xt[lk + 2][r] = xq.z; Xt[lk + 3][r] = xq.w;
            const float4 gq = *(const float4*)(W + (size_t)(n0 + r) * (2 * Hn) + k0 + lk);
            Wgt[lk + 0][r] = gq.x; Wgt[lk + 1][r] = gq.y;
            Wgt[lk + 2][r] = gq.z; Wgt[lk + 3][r] = gq.w;
            const float4 vq = *(const float4*)(W + (size_t)(n0 + r) * (2 * Hn) + Hn + k0 + lk);
            Wvt[lk + 0][r] = vq.x; Wvt[lk + 1][r] = vq.y;
            Wvt[lk + 2][r] = vq.z; Wvt[lk + 3][r] = vq.w;
        }
        __syncthreads();
#pragma unroll
        for (int k = 0; k < BK; ++k) {
            const float4 xv = *(const float4*)&Xt[k][ty * 4];
            const float4 wg = *(const float4*)&Wgt[k][tx * 4];
            const float4 wv = *(const float4*)&Wvt[k][tx * 4];
            const float xr[4]  = {xv.x, xv.y, xv.z, xv.w};
            const float wgr[4] = {wg.x, wg.y, wg.z, wg.w};
            const float wvr[4] = {wv.x, wv.y, wv.z, wv.w};
#pragma unroll
            for (int r = 0; r < 4; ++r)
#pragma unroll
                for (int c = 0; c < 4; ++c) {
                    accg[r][c] = fmaf(xr[r], wgr[c], accg[r][c]);
                    accv[r][c] = fmaf(xr[r], wvr[c], accv[r][c]);
                }
        }
        __syncthreads();
    }

    const int oc = n0 + tx * 4;
    const float4 b4 = *(const float4*)(bias + oc);
#pragma unroll
    for (int r = 0; r < 4; ++r) {
        const int m = m0 + ty * 4 + r;
        float4 go, vo;
        go.x = accg[r][0] + b4.x; go.y = accg[r][1] + b4.y;
        go.z = accg[r][2] + b4.z; go.w = accg[r][3] + b4.w;
        vo.x = accv[r][0]; vo.y = accv[r][1];
        vo.z = accv[r][2]; vo.w = accv[r][3];
        *(float4*)(g + (size_t)m * Hn + oc) = go;
        *(float4*)(v + (size_t)m * Hn + oc) = vo;
    }
}

// ---------------- Expansion: out[b,p,h] = tanh(g[b,i,h] + v[b,j,h]) --------
__device__ __forceinline__ float fast_tanh(float x) {
    // tanh(x) = (e^{2x}-1)/(e^{2x}+1); v_exp + v_rcp, rel err ~1e-6
    const float x2 = fminf(fmaxf(2.0f * x, -40.0f), 40.0f);
    const float e = __expf(x2);
    return (e - 1.0f) * __builtin_amdgcn_rcpf(e + 1.0f);
}

__global__ __launch_bounds__(256) void expand_kernel(
    const float* __restrict__ g,   // (4, 256, 768), bias already added
    const float* __restrict__ v,   // (4, 256, 768)
    float* __restrict__ out)       // (4, 32896, 768)
{
    const int p = blockIdx.x;

    // p -> (i, j): base(i) = i*Sn - i*(i-1)/2, row-major upper triangle
    int i = (int)((513.0f - sqrtf((float)(263169 - 8 * p))) * 0.5f);
    if (i < 0) i = 0;
    if (i > Sn - 1) i = Sn - 1;
    while (i > 0 && (i * Sn - (i * (i - 1)) / 2) > p) --i;
    while ((i + 1) * Sn - ((i + 1) * i) / 2 <= p) ++i;
    const int base = i * Sn - (i * (i - 1)) / 2;
    const int j = i + (p - base);

    const v4f* __restrict__ g4 = (const v4f*)g;
    const v4f* __restrict__ v4 = (const v4f*)v;
    v4f* __restrict__ o4 = (v4f*)out;
    const int HQ = Hn / 4;  // 192

    for (int t = threadIdx.x; t < Bn * HQ; t += 256) {
        const int b  = t / HQ;      // 0..3
        const int hq = t - b * HQ;  // 0..191
        const v4f gq = g4[(size_t)(b * Sn + i) * HQ + hq];
        const v4f vq = v4[(size_t)(b * Sn + j) * HQ + hq];
        v4f r;
        r.x = fast_tanh(gq.x + vq.x);
        r.y = fast_tanh(gq.y + vq.y);
        r.z = fast_tanh(gq.z + vq.z);
        r.w = fast_tanh(gq.w + vq.w);
        __builtin_nontemporal_store(r, &o4[((size_t)b * Pn + p) * HQ + hq]);
    }
}

extern "C" void kernel_launch(void* const* d_in, const int* in_sizes, int n_in,
                              void* d_out, int out_size, void* d_ws, size_t ws_size,
                              hipStream_t stream) {
    const float* X    = (const float*)d_in[0];  // (4,256,768) fp32
    const float* W    = (const float*)d_in[1];  // (768,1536) fp32
    const float* bias = (const float*)d_in[2];  // (768) fp32
    float* out = (float*)d_out;                 // (4,32896,768) fp32

    float* g = (float*)d_ws;                    // 1024*768 floats
    float* v = g + (size_t)Mn * Hn;             // 1024*768 floats (6.3 MB total)

    dim3 gg(Mn / BM, Hn / BN);                  // 16 x 12 = 192 blocks
    gemm_gv_kernel<<<gg, 256, 0, stream>>>(X, W, bias, g, v);
    expand_kernel<<<Pn, 256, 0, stream>>>(g, v, out);
}